// Round 15
// baseline (165.631 us; speedup 1.0000x reference)
//
#include <hip/hip_runtime.h>
#include <math.h>

constexpr int B  = 128;
constexpr int R  = 4096;
constexpr int IC = 8;
constexpr int C  = 10;
constexpr int O  = 16;
constexpr int CO = C * O;        // 160

constexpr int RCH    = 8;        // r's per chunk: 1024 pass blocks = 4/CU (occupancy!)
constexpr int NCHUNK = R / RCH;  // 512
constexpr int NWCONV = (R * C * O * IC) / 2048;   // 2560 W-convert blocks (8 f/thr)
constexpr int NXPOSE = (R / 16) * (B / 16);       // 2048 x-transpose blocks

using f16x8 = __attribute__((ext_vector_type(8))) _Float16;
using f16x4 = __attribute__((ext_vector_type(4))) _Float16;
using f32x4 = __attribute__((ext_vector_type(4))) float;

// DPP add (VALU). row_ror:N = 0x120|N rotates within each 16-lane row.
template<int CTRL>
__device__ __forceinline__ float dpp_add(float v) {
    return v + __int_as_float(__builtin_amdgcn_update_dpp(
        0, __float_as_int(v), CTRL, 0xF, 0xF, true));
}
__device__ __forceinline__ float rowsum16(float v) {
    v = dpp_add<0x121>(v); v = dpp_add<0x122>(v);
    v = dpp_add<0x124>(v); v = dpp_add<0x128>(v);
    return v;
}

// Butterfly sum over lane^16 / lane^32 (R12-proven DS path).
__device__ __forceinline__ float sum_kb(float p) {
    p += __int_as_float(__builtin_amdgcn_ds_swizzle(__float_as_int(p), 0x401F));
    p += __shfl_xor(p, 32, 64);
    return p;
}

// ---- fused one-time converts: W fp32->fp16 (same layout), x -> xT16 [r][b][i],
// and a 16B zero page for the routing passes' dead-k lanes. ----
__global__ __launch_bounds__(256)
void convert_kernel(const float* __restrict__ x, const float* __restrict__ W,
                    _Float16* __restrict__ W16, _Float16* __restrict__ xT16,
                    float* __restrict__ zpage)
{
    const int bid = blockIdx.x;
    const int tid = threadIdx.x;
    if (bid == 0 && tid < 4) zpage[tid] = 0.f;
    if (bid < NWCONV) {
        const size_t i = ((size_t)bid * 256 + tid) * 8;
        float4 v0 = *reinterpret_cast<const float4*>(W + i);
        float4 v1 = *reinterpret_cast<const float4*>(W + i + 4);
        f16x8 h = {(_Float16)v0.x, (_Float16)v0.y, (_Float16)v0.z, (_Float16)v0.w,
                   (_Float16)v1.x, (_Float16)v1.y, (_Float16)v1.z, (_Float16)v1.w};
        *reinterpret_cast<f16x8*>(W16 + i) = h;
    } else {
        __shared__ float tile[16][16][IC + 1];
        const int v  = bid - NWCONV;
        const int r0 = (v & 255) * 16;
        const int b0 = (v >> 8) * 16;
        {
            const int rj = tid & 15, bi = tid >> 4;   // coalesced read over r
            const float* src = x + ((size_t)(b0 + bi) * R + (r0 + rj)) * IC;
            float4 a0 = *reinterpret_cast<const float4*>(src);
            float4 a1 = *reinterpret_cast<const float4*>(src + 4);
            float* t = tile[bi][rj];
            t[0]=a0.x; t[1]=a0.y; t[2]=a0.z; t[3]=a0.w;
            t[4]=a1.x; t[5]=a1.y; t[6]=a1.z; t[7]=a1.w;
        }
        __syncthreads();
        {
            const int bi = tid & 15, rj = tid >> 4;   // coalesced write over b
            const float* t = tile[bi][rj];
            f16x8 h;
            #pragma unroll
            for (int i = 0; i < IC; ++i) h[i] = (_Float16)t[i];
            *reinterpret_cast<f16x8*>(xT16 + ((size_t)(r0 + rj) * B + (b0 + bi)) * IC) = h;
        }
    }
}

// ---- pass 0: K-packed GEMM (uniform 0.1 weights => per-r sum collapses).
// 4 r's per MFMA K=32; every lane loads real 16B; zero K-waste. ----
__global__ __launch_bounds__(256, 4)
void pass0_gemm(const _Float16* __restrict__ W16, const _Float16* __restrict__ xT16,
                _Float16* __restrict__ s_part)
{
    const int tid = threadIdx.x;
    const int wv  = tid >> 6;
    const int l   = tid & 63;
    const int ln  = l & 15;
    const int kb  = l >> 4;

    const int g     = blockIdx.x;
    const int xcd   = g & 7;
    const int t     = g >> 3;          // 0..127
    const int bhalf = t & 1;
    const int cid   = t >> 1;          // 0..63
    const int chunk = xcd * 64 + cid;  // 0..511
    const int b     = bhalf * 64 + wv * 16 + ln;
    const int r0    = chunk * RCH;

    f32x4 sacc[C];
    #pragma unroll
    for (int c = 0; c < C; ++c) sacc[c] = (f32x4){0.f, 0.f, 0.f, 0.f};

    const _Float16* xptr = xT16 + ((size_t)(r0 + kb) * B + b) * IC;
    const _Float16* wptr = W16 + ((size_t)(r0 + kb) * C * O + ln) * IC;

    #pragma unroll 2
    for (int rp = 0; rp < RCH / 4; ++rp) {
        const f16x8 bf = *reinterpret_cast<const f16x8*>(xptr);
        xptr += (size_t)4 * B * IC;
        #pragma unroll
        for (int c = 0; c < C; ++c) {
            f16x8 af = *reinterpret_cast<const f16x8*>(wptr + (size_t)c * (O * IC));
            sacc[c] = __builtin_amdgcn_mfma_f32_16x16x32_f16(af, bf, sacc[c], 0, 0, 0);
        }
        wptr += (size_t)4 * C * O * IC;
    }

    _Float16* sp = s_part + ((size_t)chunk * B + b) * CO + kb * 4;
    #pragma unroll
    for (int c = 0; c < C; ++c) {
        f16x4 h = {(_Float16)(sacc[c][0] * 0.1f), (_Float16)(sacc[c][1] * 0.1f),
                   (_Float16)(sacc[c][2] * 0.1f), (_Float16)(sacc[c][3] * 0.1f)};
        *reinterpret_cast<f16x4*>(sp + c * O) = h;
    }
}

// ---- routing pass (iters 1,2) ----
// Wave = 16 b's; kb = k-block (kb>0 lanes read the zero page so B rows 8..31
// are zero and A-garbage is annihilated). D: col=b (ln), row=o (kb*4+reg).
// unroll 2 = compiler pipelining without the R10 full-unroll spill.
// Grid 1024 = 4 blocks/CU: the occupancy fix (R14 was grid-starved at 2/CU).
template<int IT>
__global__ __launch_bounds__(256, 4)
void pass_mfma(const _Float16* __restrict__ W16, const _Float16* __restrict__ xT16,
               const float* __restrict__ vsum, const float* __restrict__ zpage,
               _Float16* __restrict__ s_part)
{
    const int tid = threadIdx.x;
    const int wv  = tid >> 6;
    const int l   = tid & 63;
    const int ln  = l & 15;
    const int kb  = l >> 4;

    const int g     = blockIdx.x;
    const int xcd   = g & 7;
    const int t     = g >> 3;          // 0..127
    const int bhalf = t & 1;
    const int cid   = t >> 1;          // 0..63
    const int chunk = xcd * 64 + cid;  // 0..511
    const int b     = bhalf * 64 + wv * 16 + ln;
    const int r0    = chunk * RCH;

    float vreg[C][4];                  // v[b][c][o = kb*4 + j]
    #pragma unroll
    for (int c = 0; c < C; ++c)
        *reinterpret_cast<float4*>(vreg[c]) =
            *reinterpret_cast<const float4*>(vsum + (size_t)b * CO + c * O + kb * 4);

    f32x4 sacc[C];
    #pragma unroll
    for (int c = 0; c < C; ++c) sacc[c] = (f32x4){0.f, 0.f, 0.f, 0.f};

    const _Float16* xptr = (kb == 0)
        ? (xT16 + ((size_t)r0 * B + b) * IC)
        : reinterpret_cast<const _Float16*>(zpage);
    const ptrdiff_t xstep = (kb == 0) ? (ptrdiff_t)B * IC : 0;
    const _Float16* wptr = W16 + ((size_t)r0 * C * O + ln) * IC;

    #pragma unroll 2
    for (int rr = 0; rr < RCH; ++rr) {
        const f16x8 bf = *reinterpret_cast<const f16x8*>(xptr);
        xptr += xstep;

        f32x4 uh[C];
        #pragma unroll
        for (int c = 0; c < C; ++c) {
            f16x8 af = *reinterpret_cast<const f16x8*>(wptr + (size_t)c * (O * IC));
            uh[c] = __builtin_amdgcn_mfma_f32_16x16x32_f16(
                        af, bf, (f32x4){0.f, 0.f, 0.f, 0.f}, 0, 0, 0);
        }
        wptr += C * O * IC;

        // logits a[b,c] = sum_o uh*v: 4 in-lane FMA + DS butterfly
        float a[C];
        #pragma unroll
        for (int c = 0; c < C; ++c) {
            float p = uh[c][0] * vreg[c][0];
            p = fmaf(uh[c][1], vreg[c][1], p);
            p = fmaf(uh[c][2], vreg[c][2], p);
            p = fmaf(uh[c][3], vreg[c][3], p);
            a[c] = sum_kb(p);
        }
        // softmax over c (logits small: no max-subtract), rcp divide
        float sum = 0.f;
        #pragma unroll
        for (int c = 0; c < C; ++c) { a[c] = __expf(a[c]); sum += a[c]; }
        const float inv = __builtin_amdgcn_rcpf(sum);
        #pragma unroll
        for (int c = 0; c < C; ++c) {
            const float wgt = a[c] * inv;
            #pragma unroll
            for (int j = 0; j < 4; ++j)
                sacc[c][j] = fmaf(wgt, uh[c][j], sacc[c][j]);
        }
    }

    _Float16* sp = s_part + ((size_t)chunk * B + b) * CO + kb * 4;
    #pragma unroll
    for (int c = 0; c < C; ++c) {
        f16x4 h = {(_Float16)sacc[c][0], (_Float16)sacc[c][1],
                   (_Float16)sacc[c][2], (_Float16)sacc[c][3]};
        *reinterpret_cast<f16x4*>(sp + c * O) = h;
    }
}

// Sum fp16 partials over chunks, add bias, squash. Block = one (b, c).
__global__ __launch_bounds__(256)
void reduce_squash(const _Float16* __restrict__ s_part, const float* __restrict__ bias,
                   const float* __restrict__ vin_sum,
                   float* __restrict__ v_out, float* __restrict__ vsum_out)
{
    const int b = blockIdx.x;
    const int c = blockIdx.y;
    const int t = threadIdx.x;
    const int o = t & 15;
    const int q = t >> 4;            // 16 segments of NCHUNK/16 chunks

    float acc = 0.f;
    for (int k = 0; k < NCHUNK / 16; ++k) {
        const int blk = q * (NCHUNK / 16) + k;
        acc += (float)s_part[((size_t)blk * B + b) * CO + c * O + o];
    }
    __shared__ float red[16][O];
    red[q][o] = acc;
    __syncthreads();

    if (t < O) {
        float s = bias[c * O + o];
        #pragma unroll
        for (int k = 0; k < 16; ++k) s += red[k][o];
        float n = rowsum16(s * s);                     // ||s||^2 over o
        float v = s * sqrtf(n) / (1.f + n);            // squash
        const size_t idx = (size_t)b * CO + c * O + o;
        if (v_out)    v_out[idx] = v;
        if (vsum_out) vsum_out[idx] = (vin_sum ? vin_sum[idx] : 0.f) + v;
    }
}

extern "C" void kernel_launch(void* const* d_in, const int* in_sizes, int n_in,
                              void* d_out, int out_size, void* d_ws, size_t ws_size,
                              hipStream_t stream)
{
    const float* x    = (const float*)d_in[0];
    const float* W    = (const float*)d_in[1];
    const float* bias = (const float*)d_in[2];
    float* out = (float*)d_out;

    float* ws      = (float*)d_ws;
    float* vsumA   = ws;                                    // 20,480 f
    float* vsumB   = vsumA + (size_t)B * CO;                // 20,480 f
    float* zpage   = vsumB + (size_t)B * CO;                // 4 f (16B zeros)
    _Float16* s_part = (_Float16*)(zpage + 4);              // 512*128*160 halves (21 MB)
    _Float16* W16    = s_part + (size_t)NCHUNK * B * CO;    // 5,242,880 halves
    _Float16* xT16   = W16 + (size_t)R * C * O * IC;        // 4,194,304 halves
    // total ~40 MB

    convert_kernel<<<NWCONV + NXPOSE, 256, 0, stream>>>(x, W, W16, xT16, zpage);

    dim3 pg(NCHUNK * 2);     // 1024 blocks = 4 per CU, XCD-decoded in-kernel
    dim3 rg(B, C);

    // iter 0: uniform 0.1 weights — K-packed pure GEMM
    pass0_gemm<<<pg, 256, 0, stream>>>(W16, xT16, s_part);
    reduce_squash<<<rg, 256, 0, stream>>>(s_part, bias, nullptr, nullptr, vsumA);  // vsumA = v0
    // iter 1: logits = uh . v0
    pass_mfma<1><<<pg, 256, 0, stream>>>(W16, xT16, vsumA, zpage, s_part);
    reduce_squash<<<rg, 256, 0, stream>>>(s_part, bias, vsumA, nullptr, vsumB);    // vsumB = v0+v1
    // iter 2: logits = uh . (v0+v1)
    pass_mfma<2><<<pg, 256, 0, stream>>>(W16, xT16, vsumB, zpage, s_part);
    reduce_squash<<<rg, 256, 0, stream>>>(s_part, bias, nullptr, out, nullptr);    // out = v2
}

// Round 16
// 109.481 us; speedup vs baseline: 1.5129x; 1.5129x over previous
//
#include <hip/hip_runtime.h>
#include <math.h>

constexpr int B  = 128;
constexpr int R  = 4096;
constexpr int IC = 8;
constexpr int C  = 10;
constexpr int O  = 16;
constexpr int CO = C * O;        // 160

constexpr int RCH    = 8;        // r's per chunk: 1024 pass blocks, 4 waves/SIMD
constexpr int NCHUNK = R / RCH;  // 512
constexpr int NWCONV = (R * C * O * IC) / 1024;   // 5120 W-convert blocks (4 f/thr)
constexpr int NXPOSE = (R / 16) * (B / 16);       // 2048 x-transpose blocks

using f16x8 = __attribute__((ext_vector_type(8))) _Float16;
using f16x4 = __attribute__((ext_vector_type(4))) _Float16;
using f32x4 = __attribute__((ext_vector_type(4))) float;

// DPP add (VALU). row_ror:N = 0x120|N rotates within each 16-lane row.
template<int CTRL>
__device__ __forceinline__ float dpp_add(float v) {
    return v + __int_as_float(__builtin_amdgcn_update_dpp(
        0, __float_as_int(v), CTRL, 0xF, 0xF, true));
}
__device__ __forceinline__ float rowsum16(float v) {
    v = dpp_add<0x121>(v); v = dpp_add<0x122>(v);
    v = dpp_add<0x124>(v); v = dpp_add<0x128>(v);
    return v;
}

// Butterfly sum over lane^16 / lane^32 (R12-proven DS path).
__device__ __forceinline__ float sum_kb(float p) {
    p += __int_as_float(__builtin_amdgcn_ds_swizzle(__float_as_int(p), 0x401F));
    p += __shfl_xor(p, 32, 64);
    return p;
}

// ---- fused one-time converts: W fp32->fp16 (same layout) + x -> xT16 [r][b][i] ----
__global__ __launch_bounds__(256)
void convert_kernel(const float* __restrict__ x, const float* __restrict__ W,
                    _Float16* __restrict__ W16, _Float16* __restrict__ xT16)
{
    const int bid = blockIdx.x;
    const int tid = threadIdx.x;
    if (bid < NWCONV) {
        const size_t i = ((size_t)bid * 256 + tid) * 4;
        float4 v = *reinterpret_cast<const float4*>(W + i);
        f16x4 h = {(_Float16)v.x, (_Float16)v.y, (_Float16)v.z, (_Float16)v.w};
        *reinterpret_cast<f16x4*>(W16 + i) = h;
    } else {
        __shared__ float tile[16][16][IC + 1];
        const int v  = bid - NWCONV;
        const int r0 = (v & 255) * 16;
        const int b0 = (v >> 8) * 16;
        {
            const int rj = tid & 15, bi = tid >> 4;   // coalesced read over r
            const float* src = x + ((size_t)(b0 + bi) * R + (r0 + rj)) * IC;
            float4 a0 = *reinterpret_cast<const float4*>(src);
            float4 a1 = *reinterpret_cast<const float4*>(src + 4);
            float* t = tile[bi][rj];
            t[0]=a0.x; t[1]=a0.y; t[2]=a0.z; t[3]=a0.w;
            t[4]=a1.x; t[5]=a1.y; t[6]=a1.z; t[7]=a1.w;
        }
        __syncthreads();
        {
            const int bi = tid & 15, rj = tid >> 4;   // coalesced write over b
            const float* t = tile[bi][rj];
            f16x8 h;
            #pragma unroll
            for (int i = 0; i < IC; ++i) h[i] = (_Float16)t[i];
            *reinterpret_cast<f16x8*>(xT16 + ((size_t)(r0 + rj) * B + (b0 + bi)) * IC) = h;
        }
    }
}

// ---- pass 0: K-packed GEMM (uniform 0.1 weights => per-r sum collapses).
// 4 r's per MFMA K=32; every lane loads real 16B; zero K-waste. ----
__global__ __launch_bounds__(256, 4)
void pass0_gemm(const _Float16* __restrict__ W16, const _Float16* __restrict__ xT16,
                float* __restrict__ s_part)
{
    const int tid = threadIdx.x;
    const int wv  = tid >> 6;
    const int l   = tid & 63;
    const int ln  = l & 15;
    const int kb  = l >> 4;

    const int g     = blockIdx.x;
    const int xcd   = g & 7;
    const int t     = g >> 3;          // 0..127
    const int bhalf = t & 1;
    const int cid   = t >> 1;          // 0..63
    const int chunk = xcd * 64 + cid;  // 0..511
    const int b     = bhalf * 64 + wv * 16 + ln;
    const int r0    = chunk * RCH;

    f32x4 sacc[C];
    #pragma unroll
    for (int c = 0; c < C; ++c) sacc[c] = (f32x4){0.f, 0.f, 0.f, 0.f};

    const _Float16* xptr = xT16 + ((size_t)(r0 + kb) * B + b) * IC;
    const _Float16* wptr = W16 + ((size_t)(r0 + kb) * C * O + ln) * IC;

    #pragma unroll 2
    for (int rp = 0; rp < RCH / 4; ++rp) {
        const f16x8 bf = *reinterpret_cast<const f16x8*>(xptr);
        xptr += (size_t)4 * B * IC;
        #pragma unroll
        for (int c = 0; c < C; ++c) {
            f16x8 af = *reinterpret_cast<const f16x8*>(wptr + (size_t)c * (O * IC));
            sacc[c] = __builtin_amdgcn_mfma_f32_16x16x32_f16(af, bf, sacc[c], 0, 0, 0);
        }
        wptr += (size_t)4 * C * O * IC;
    }

    float* sp = s_part + ((size_t)chunk * B + b) * CO + kb * 4;
    #pragma unroll
    for (int c = 0; c < C; ++c)
        *reinterpret_cast<float4*>(sp + c * O) =
            make_float4(sacc[c][0] * 0.1f, sacc[c][1] * 0.1f,
                        sacc[c][2] * 0.1f, sacc[c][3] * 0.1f);
}

// ---- routing pass (iters 1,2) — the proven R12 body, RCH=8 geometry ----
// Wave = 16 b's; kb = k-block (only kb==0 carries real k; bf masked to zero
// for kb>0, so B rows 8..31 annihilate A-garbage).
// D: col=b (ln), row=o (kb*4+reg). unroll 2 = pipelining without full-unroll
// spill. (256,3): VGPR cap ~170 fits; (256,4) spilled 87 MB in R15.
template<int IT>
__global__ __launch_bounds__(256, 3)
void pass_mfma(const _Float16* __restrict__ W16, const _Float16* __restrict__ xT16,
               const float* __restrict__ vsum, float* __restrict__ s_part)
{
    const int tid = threadIdx.x;
    const int wv  = tid >> 6;
    const int l   = tid & 63;
    const int ln  = l & 15;
    const int kb  = l >> 4;

    const int g     = blockIdx.x;
    const int xcd   = g & 7;
    const int t     = g >> 3;          // 0..127
    const int bhalf = t & 1;
    const int cid   = t >> 1;          // 0..63
    const int chunk = xcd * 64 + cid;  // 0..511
    const int b     = bhalf * 64 + wv * 16 + ln;
    const int r0    = chunk * RCH;

    float vreg[C][4];                  // v[b][c][o = kb*4 + j]
    #pragma unroll
    for (int c = 0; c < C; ++c)
        *reinterpret_cast<float4*>(vreg[c]) =
            *reinterpret_cast<const float4*>(vsum + (size_t)b * CO + c * O + kb * 4);

    f32x4 sacc[C];
    #pragma unroll
    for (int c = 0; c < C; ++c) sacc[c] = (f32x4){0.f, 0.f, 0.f, 0.f};

    const _Float16* xptr = xT16 + ((size_t)r0 * B + b) * IC;
    const _Float16* wptr = W16 + ((size_t)r0 * C * O + ln) * IC;

    #pragma unroll 2
    for (int rr = 0; rr < RCH; ++rr) {
        f16x8 bf;
        #pragma unroll
        for (int j = 0; j < 8; ++j) bf[j] = (_Float16)0.f;
        if (kb == 0) bf = *reinterpret_cast<const f16x8*>(xptr);
        xptr += (size_t)B * IC;

        f32x4 uh[C];
        #pragma unroll
        for (int c = 0; c < C; ++c) {
            f16x8 af = *reinterpret_cast<const f16x8*>(wptr + (size_t)c * (O * IC));
            uh[c] = __builtin_amdgcn_mfma_f32_16x16x32_f16(
                        af, bf, (f32x4){0.f, 0.f, 0.f, 0.f}, 0, 0, 0);
        }
        wptr += C * O * IC;

        // logits a[b,c] = sum_o uh*v: 4 in-lane FMA + DS butterfly
        float a[C];
        #pragma unroll
        for (int c = 0; c < C; ++c) {
            float p = uh[c][0] * vreg[c][0];
            p = fmaf(uh[c][1], vreg[c][1], p);
            p = fmaf(uh[c][2], vreg[c][2], p);
            p = fmaf(uh[c][3], vreg[c][3], p);
            a[c] = sum_kb(p);
        }
        // softmax over c (logits small: no max-subtract), rcp divide
        float sum = 0.f;
        #pragma unroll
        for (int c = 0; c < C; ++c) { a[c] = __expf(a[c]); sum += a[c]; }
        const float inv = __builtin_amdgcn_rcpf(sum);
        #pragma unroll
        for (int c = 0; c < C; ++c) {
            const float wgt = a[c] * inv;
            #pragma unroll
            for (int j = 0; j < 4; ++j)
                sacc[c][j] = fmaf(wgt, uh[c][j], sacc[c][j]);
        }
    }

    float* sp = s_part + ((size_t)chunk * B + b) * CO + kb * 4;
    #pragma unroll
    for (int c = 0; c < C; ++c)
        *reinterpret_cast<float4*>(sp + c * O) =
            make_float4(sacc[c][0], sacc[c][1], sacc[c][2], sacc[c][3]);
}

// Sum partials over chunks, add bias, squash. Block = one (b, c).
__global__ __launch_bounds__(256)
void reduce_squash(const float* __restrict__ s_part, const float* __restrict__ bias,
                   const float* __restrict__ vin_sum,
                   float* __restrict__ v_out, float* __restrict__ vsum_out)
{
    const int b = blockIdx.x;
    const int c = blockIdx.y;
    const int t = threadIdx.x;
    const int o = t & 15;
    const int q = t >> 4;            // 16 segments of NCHUNK/16 chunks

    float acc = 0.f;
    for (int k = 0; k < NCHUNK / 16; ++k) {
        const int blk = q * (NCHUNK / 16) + k;
        acc += s_part[((size_t)blk * B + b) * CO + c * O + o];
    }
    __shared__ float red[16][O];
    red[q][o] = acc;
    __syncthreads();

    if (t < O) {
        float s = bias[c * O + o];
        #pragma unroll
        for (int k = 0; k < 16; ++k) s += red[k][o];
        float n = rowsum16(s * s);                     // ||s||^2 over o
        float v = s * sqrtf(n) / (1.f + n);            // squash
        const size_t idx = (size_t)b * CO + c * O + o;
        if (v_out)    v_out[idx] = v;
        if (vsum_out) vsum_out[idx] = (vin_sum ? vin_sum[idx] : 0.f) + v;
    }
}

extern "C" void kernel_launch(void* const* d_in, const int* in_sizes, int n_in,
                              void* d_out, int out_size, void* d_ws, size_t ws_size,
                              hipStream_t stream)
{
    const float* x    = (const float*)d_in[0];
    const float* W    = (const float*)d_in[1];
    const float* bias = (const float*)d_in[2];
    float* out = (float*)d_out;

    float* ws     = (float*)d_ws;
    float* s_part = ws;                                     // 512*128*160 f (42 MB)
    float* vsumA  = s_part + (size_t)NCHUNK * B * CO;       // 20,480 f
    float* vsumB  = vsumA + (size_t)B * CO;                 // 20,480 f
    _Float16* W16  = (_Float16*)(vsumB + (size_t)B * CO);   // 5,242,880 halves
    _Float16* xT16 = W16 + (size_t)R * C * O * IC;          // 4,194,304 halves
    // total ~61 MB

    convert_kernel<<<NWCONV + NXPOSE, 256, 0, stream>>>(x, W, W16, xT16);

    dim3 pg(NCHUNK * 2);     // 1024 blocks, XCD-decoded in-kernel
    dim3 rg(B, C);

    // iter 0: uniform 0.1 weights — K-packed pure GEMM
    pass0_gemm<<<pg, 256, 0, stream>>>(W16, xT16, s_part);
    reduce_squash<<<rg, 256, 0, stream>>>(s_part, bias, nullptr, nullptr, vsumA);  // vsumA = v0
    // iter 1: logits = uh . v0
    pass_mfma<1><<<pg, 256, 0, stream>>>(W16, xT16, vsumA, s_part);
    reduce_squash<<<rg, 256, 0, stream>>>(s_part, bias, vsumA, nullptr, vsumB);    // vsumB = v0+v1
    // iter 2: logits = uh . (v0+v1)
    pass_mfma<2><<<pg, 256, 0, stream>>>(W16, xT16, vsumB, s_part);
    reduce_squash<<<rg, 256, 0, stream>>>(s_part, bias, nullptr, out, nullptr);    // out = v2
}